// Round 8
// baseline (224.678 us; speedup 1.0000x reference)
//
#include <hip/hip_runtime.h>
#include <math.h>

typedef __attribute__((ext_vector_type(8))) short short8;
typedef __attribute__((ext_vector_type(4))) float f32x4;
typedef __attribute__((ext_vector_type(4))) _Float16 h16x4;

#define BB  4
#define C1  128
#define C2  256
#define HH  128
#define WW  128
#define NPT 9
#define HWN (HH*WW)

// ---- workspace byte offsets (all 256-aligned) ----
#define XT_OFF    0ull                        // bf16 xT[b][h][w][c]   : 16,777,216 B
#define WB3_OFF   16777216ull                 // bf16 wB3[n][ob][kc][lane][8] : 589,824 B
#define WOF32_OFF (WB3_OFF + 589824ull)       // f32  wof32[c][q][81]  :     82,944 B
#define BN_OFF    (WOF32_OFF + 82944ull)      // f32  bnA/bnB[256]     :      2,048 B
#define OFFP_OFF  (BN_OFF + 2048ull)          // f32  offp[pos][20]    :  5,242,880 B

__device__ __forceinline__ ushort f2bf(float f) {
  uint u = __builtin_bit_cast(uint, f);
  u += 0x7FFFu + ((u >> 16) & 1u);            // RNE
  return (ushort)(u >> 16);
}
__device__ __forceinline__ float bf2f(ushort u) {
  return __builtin_bit_cast(float, ((uint)u) << 16);
}

// ---------------- weight / BN prep ----------------
// wB3 element t: j=t&7, lane=(t>>3)&63, kc=(t>>9)&3, ob=(t>>11)&15, n=t>>15
//   -> o = ob*16 + (lane&15), c = kc*32 + (lane>>4)*8 + j
__global__ __launch_bounds__(256) void prep(
    const float* __restrict__ w_main, const float* __restrict__ w_off,
    const float* __restrict__ g, const float* __restrict__ be,
    const float* __restrict__ mu, const float* __restrict__ var,
    ushort* ws_u, float* ws_f) {
  int t = blockIdx.x * 256 + threadIdx.x;
  if (t < C1 * NPT * C2) {
    int j = t & 7, lane = (t >> 3) & 63, kc = (t >> 9) & 3;
    int ob = (t >> 11) & 15, n = t >> 15;
    int o = ob * 16 + (lane & 15);
    int c = kc * 32 + (lane >> 4) * 8 + j;
    ws_u[WB3_OFF / 2 + t] = f2bf(w_main[(o * C1 + c) * NPT + n]);
  } else if (t < C1 * NPT * C2 + 128 * 2 * 81) {  // wof32[(c*2+q)*81 + tap*9 + i]
    int e = t - C1 * NPT * C2;
    int c2 = e / 81, r81 = e - c2 * 81;
    int q = c2 & 1, c = c2 >> 1;
    int tap = r81 / 9, i = r81 - tap * 9;
    int oc = q * 9 + i;
    ws_f[WOF32_OFF / 4 + e] = w_off[(oc * C1 + c) * 9 + tap];
  } else if (t < C1 * NPT * C2 + 128 * 2 * 81 + C2) {
    int o = t - (C1 * NPT * C2 + 128 * 2 * 81);
    float inv = g[o] * rsqrtf(var[o] + 1e-5f);
    ws_f[BN_OFF / 4 + o] = inv;
    ws_f[BN_OFF / 4 + 256 + o] = be[o] - mu[o] * inv;
  }
}

// ---------------- x -> xT[b][h][w][c] bf16 (c-contiguous) ----------------
__global__ __launch_bounds__(256) void transpose_x(
    const float* __restrict__ x, ushort* ws_u) {
  __shared__ __align__(16) ushort tile[32][68];
  int bid = blockIdx.x;
  int wt = bid & 1, h = (bid >> 1) & 127, cb = (bid >> 8) & 3, b = bid >> 10;
  int c0 = cb * 32, w0 = wt * 64;
  int tid = threadIdx.x;
  int wl = tid & 63, rr = tid >> 6;
#pragma unroll
  for (int it = 0; it < 8; ++it) {
    int ci = it * 4 + rr;
    tile[ci][wl] = f2bf(x[(((size_t)b * C1 + c0 + ci) * HWN) + h * WW + w0 + wl]);
  }
  __syncthreads();
  int wl2 = tid >> 2, cg = tid & 3;
  short8 pk;
#pragma unroll
  for (int k = 0; k < 8; ++k) pk[k] = (short)tile[cg * 8 + k][wl2];
  *(short8*)(ws_u + XT_OFF / 2 +
             (((size_t)(b * HH + h) * WW + w0 + wl2) * C1 + c0 + cg * 8)) = pk;
}

// ---------------- fp32 offset conv, channel-split x4, no LDS, no barriers ----------------
__global__ __launch_bounds__(256) void off_conv_part(
    const float* __restrict__ x, const float* __restrict__ b_off,
    const float* __restrict__ ws_f, float* __restrict__ part) {
  int blk = blockIdx.x;
  int cg = blk & 3, bh = blk >> 2;
  int h = bh & 127, b = bh >> 7;
  int tid = threadIdx.x;
  int w = tid & 127, q = tid >> 7;
  int qu = __builtin_amdgcn_readfirstlane(q);
  const float* wq = ws_f + WOF32_OFF / 4 + qu * 81;
  const float* xb = x + ((size_t)b * C1 + cg * 32) * HWN;

  float acc[9];
#pragma unroll
  for (int i = 0; i < 9; ++i) acc[i] = (cg == 0) ? b_off[qu * 9 + i] : 0.f;

  int hc0 = (h >= 1) ? h - 1 : 0, hc2 = (h < 127) ? h + 1 : 127;
  int wc0 = (w >= 1) ? w - 1 : 0, wc2 = (w < 127) ? w + 1 : 127;
  bool vh0 = (h >= 1), vh2 = (h < 127);
  bool vw0 = (w >= 1), vw2 = (w < 127);
  int o[9];
  o[0] = hc0 * 128 + wc0; o[1] = hc0 * 128 + w; o[2] = hc0 * 128 + wc2;
  o[3] = h   * 128 + wc0; o[4] = h   * 128 + w; o[5] = h   * 128 + wc2;
  o[6] = hc2 * 128 + wc0; o[7] = hc2 * 128 + w; o[8] = hc2 * 128 + wc2;
  bool vm[9];
  vm[0] = vh0 && vw0; vm[1] = vh0; vm[2] = vh0 && vw2;
  vm[3] = vw0;        vm[4] = true; vm[5] = vw2;
  vm[6] = vh2 && vw0; vm[7] = vh2; vm[8] = vh2 && vw2;

  for (int ci = 0; ci < 32; ++ci) {
    const float* xc = xb + (size_t)ci * HWN;
    float xv[9];
#pragma unroll
    for (int k = 0; k < 9; ++k) {
      float r = xc[o[k]];
      xv[k] = vm[k] ? r : 0.f;
    }
    const float* wp = wq + (cg * 32 + ci) * 162;
#pragma unroll
    for (int tap = 0; tap < 9; ++tap)
#pragma unroll
      for (int i = 0; i < 9; ++i)
        acc[i] = fmaf(xv[tap], wp[tap * 9 + i], acc[i]);
  }
  int pos = (b * HH + h) * WW + w;
  float* pd = part + ((size_t)cg * 65536 + pos) * 20 + qu * 9;
#pragma unroll
  for (int i = 0; i < 9; ++i) pd[i] = acc[i];
}

// ---------------- reduce 4 partials -> offp ----------------
__global__ __launch_bounds__(256) void off_reduce(
    const float* __restrict__ part, float* __restrict__ ws_f) {
  int e = blockIdx.x * 256 + threadIdx.x;
  if (e >= 65536 * 18) return;
  int pos = e / 18, oc = e - pos * 18;
  size_t i0 = (size_t)pos * 20 + oc;
  float s = part[i0]
          + part[i0 + (size_t)65536 * 20]
          + part[i0 + (size_t)2 * 65536 * 20]
          + part[i0 + (size_t)3 * 65536 * 20];
  ws_f[OFFP_OFF / 4 + i0] = s;
}

// ---------------- fused gather + MFMA GEMM + BN + SiLU (8-wave, 4 blk/CU) ----------------
#define ALDS_STRIDE 136   // ushorts per 64-pos row (128 + 8 pad) -> 2-way banks
__global__ __launch_bounds__(512, 8) void akconv_main_mfma8(
    const ushort* ws_u, const float* ws_f, float* out) {
  __shared__ ushort sxy[576];                       // (x0<<8)|y0
  __shared__ __align__(8) h16x4 swgt16[576];        // 4 bilinear weights, fp16
  __shared__ __align__(16) ushort alds[2][64 * ALDS_STRIDE];

  int tid = threadIdx.x;
  int blk = blockIdx.x;
  // XCD-aware decode: each XCD (blk&7) owns one b-plane and one 64-row h-band
  int xcd = blk & 7, idx = blk >> 3;
  int b  = xcd >> 1;
  int h  = ((xcd & 1) << 6) + (idx >> 1);
  int wt = idx & 1;
  int w0 = wt * 64;
  const float* offp = ws_f + OFFP_OFF / 4;

  // phase A: bilinear sample (x0,y0) + 4 weights for 64 positions x 9 points
  for (int t = tid; t < 576; t += 512) {
    int n = t >> 6, wl = t & 63;
    int pos = (b * HH + h) * WW + w0 + wl;
    float ox = offp[pos * 20 + n];
    float oy = offp[pos * 20 + 9 + n];
    float px = ox + (float)(n / 3) + (float)h;
    float py = oy + (float)(n - (n / 3) * 3) + (float)(w0 + wl);
    px = fminf(fmaxf(px, 0.f), 127.f);
    py = fminf(fmaxf(py, 0.f), 127.f);
    float x0 = floorf(px), y0 = floorf(py);
    float x1 = fminf(x0 + 1.f, 127.f), y1 = fminf(y0 + 1.f, 127.f);
    h16x4 g;
    g[0] = (_Float16)((1.f + (x0 - px)) * (1.f + (y0 - py)));
    g[1] = (_Float16)((1.f - (x1 - px)) * (1.f - (y1 - py)));
    g[2] = (_Float16)((1.f + (x0 - px)) * (1.f - (y1 - py)));
    g[3] = (_Float16)((1.f - (x1 - px)) * (1.f + (y0 - py)));
    sxy[t] = (ushort)(((int)x0 << 8) | (int)y0);
    swgt16[t] = g;
  }

  const char* xTb = (const char*)ws_u + (size_t)b * (HWN * 256);
  const ushort* wB3 = ws_u + WB3_OFF / 2;
  int lane = tid & 63, r = lane & 15, kg = lane >> 4;
  int obu = __builtin_amdgcn_readfirstlane(tid >> 6) * 2;  // wave's o-block (16-wide) base

  // per-thread build slots: two of (pos, 16B c-octet)
  int p0  = tid >> 4;                 // 0..31
  int p1  = p0 + 32;                  // 32..63
  int oct = tid & 15;
  int coff = oct * 16;                // byte offset within 256B c-row
  int wr0 = p0 * ALDS_STRIDE + oct * 8;
  int wr1 = p1 * ALDS_STRIDE + oct * 8;

  f32x4 acc[4][2];
#pragma unroll
  for (int mi = 0; mi < 4; ++mi)
#pragma unroll
    for (int oi = 0; oi < 2; ++oi) acc[mi][oi] = (f32x4)0.0f;

  __syncthreads();   // sxy/swgt16 visible

  short8 gv[2][4];
  f32x4 gw0, gw1;

#define GLOAD(nn)                                                       \
  {                                                                     \
    int e0 = sxy[(nn) * 64 + p0];                                       \
    int e1 = sxy[(nn) * 64 + p1];                                       \
    h16x4 hw0 = swgt16[(nn) * 64 + p0];                                 \
    h16x4 hw1 = swgt16[(nn) * 64 + p1];                                 \
    gw0[0] = (float)hw0[0]; gw0[1] = (float)hw0[1];                     \
    gw0[2] = (float)hw0[2]; gw0[3] = (float)hw0[3];                     \
    gw1[0] = (float)hw1[0]; gw1[1] = (float)hw1[1];                     \
    gw1[2] = (float)hw1[2]; gw1[3] = (float)hw1[3];                     \
    int ax0 = e0 >> 8, ay0 = e0 & 255;                                  \
    int ax1 = min(ax0 + 1, 127), ay1 = min(ay0 + 1, 127);               \
    int bx0 = e1 >> 8, by0 = e1 & 255;                                  \
    int bx1 = min(bx0 + 1, 127), by1 = min(by0 + 1, 127);               \
    gv[0][0] = *(const short8*)(xTb + (ax0 << 15) + (ay0 << 8) + coff); \
    gv[0][1] = *(const short8*)(xTb + (ax1 << 15) + (ay1 << 8) + coff); \
    gv[0][2] = *(const short8*)(xTb + (ax0 << 15) + (ay1 << 8) + coff); \
    gv[0][3] = *(const short8*)(xTb + (ax1 << 15) + (ay0 << 8) + coff); \
    gv[1][0] = *(const short8*)(xTb + (bx0 << 15) + (by0 << 8) + coff); \
    gv[1][1] = *(const short8*)(xTb + (bx1 << 15) + (by1 << 8) + coff); \
    gv[1][2] = *(const short8*)(xTb + (bx0 << 15) + (by1 << 8) + coff); \
    gv[1][3] = *(const short8*)(xTb + (bx1 << 15) + (by0 << 8) + coff); \
  }

#define GCOMBINE(bufb)                                                  \
  {                                                                     \
    short8 pk0, pk1;                                                    \
    _Pragma("unroll")                                                   \
    for (int j = 0; j < 8; ++j) {                                       \
      float f0 = gw0[0] * bf2f((ushort)gv[0][0][j])                     \
               + gw0[1] * bf2f((ushort)gv[0][1][j])                     \
               + gw0[2] * bf2f((ushort)gv[0][2][j])                     \
               + gw0[3] * bf2f((ushort)gv[0][3][j]);                    \
      float f1 = gw1[0] * bf2f((ushort)gv[1][0][j])                     \
               + gw1[1] * bf2f((ushort)gv[1][1][j])                     \
               + gw1[2] * bf2f((ushort)gv[1][2][j])                     \
               + gw1[3] * bf2f((ushort)gv[1][3][j]);                    \
      pk0[j] = (short)f2bf(f0);                                         \
      pk1[j] = (short)f2bf(f1);                                         \
    }                                                                   \
    *(short8*)(&alds[bufb][wr0]) = pk0;                                 \
    *(short8*)(&alds[bufb][wr1]) = pk1;                                 \
  }

  // prologue: build n=0 into buf 0
  GLOAD(0);
  GCOMBINE(0);
  __syncthreads();

  for (int n = 0; n < 9; ++n) {
    int buf = n & 1;
    // 1) issue next-n gathers (latency hidden by 8-wave/SIMD TLP)
    if (n < 8) GLOAD(n + 1);
    // 2) MFMA over the current 128-channel slab; B-loads are contiguous 1KB/wave
#pragma unroll
    for (int kc = 0; kc < 4; ++kc) {
      short8 b0 = *(const short8*)(wB3 + ((((size_t)(n * 16 + obu) * 4 + kc) * 64 + lane) * 8));
      short8 b1 = *(const short8*)(wB3 + ((((size_t)(n * 16 + obu + 1) * 4 + kc) * 64 + lane) * 8));
#pragma unroll
      for (int mi = 0; mi < 4; ++mi) {
        short8 a = *(const short8*)(&alds[buf][(mi * 16 + r) * ALDS_STRIDE + (kc * 4 + kg) * 8]);
        acc[mi][0] = __builtin_amdgcn_mfma_f32_16x16x32_bf16(b0, a, acc[mi][0], 0, 0, 0);
        acc[mi][1] = __builtin_amdgcn_mfma_f32_16x16x32_bf16(b1, a, acc[mi][1], 0, 0, 0);
      }
    }
    // 3) combine + write next slab
    if (n < 8) GCOMBINE(buf ^ 1);
    __syncthreads();
  }
#undef GLOAD
#undef GCOMBINE

  // epilogue: BN + SiLU, coalesced along w (col = position)
  const float* bnA = ws_f + BN_OFF / 4;
  const float* bnB = bnA + 256;
  int owu = obu * 16;
#pragma unroll
  for (int oi = 0; oi < 2; ++oi) {
#pragma unroll
    for (int mi = 0; mi < 4; ++mi) {
#pragma unroll
      for (int j = 0; j < 4; ++j) {
        int o = owu + oi * 16 + kg * 4 + j;
        float sA = bnA[o], sB = bnB[o];
        float v = acc[mi][oi][j] * sA + sB;
        float sv = v / (1.f + __expf(-v));
        out[(((size_t)b * C2 + o) * HWN) + h * WW + w0 + mi * 16 + r] = sv;
      }
    }
  }
}

extern "C" void kernel_launch(void* const* d_in, const int* in_sizes, int n_in,
                              void* d_out, int out_size, void* d_ws, size_t ws_size,
                              hipStream_t stream) {
  const float* x        = (const float*)d_in[0];
  const float* w_off    = (const float*)d_in[1];
  const float* b_off    = (const float*)d_in[2];
  const float* w_main   = (const float*)d_in[3];
  const float* bn_gamma = (const float*)d_in[4];
  const float* bn_beta  = (const float*)d_in[5];
  const float* bn_mean  = (const float*)d_in[6];
  const float* bn_var   = (const float*)d_in[7];
  ushort* ws_u = (ushort*)d_ws;
  float*  ws_f = (float*)d_ws;
  float*  out  = (float*)d_out;

  int prep_tasks = C1 * NPT * C2 + 128 * 2 * 81 + C2;   // 315904
  prep<<<(prep_tasks + 255) / 256, 256, 0, stream>>>(
      w_main, w_off, bn_gamma, bn_beta, bn_mean, bn_var, ws_u, ws_f);
  transpose_x<<<BB * 4 * HH * 2, 256, 0, stream>>>(x, ws_u);
  // offset conv: partials into d_out scratch (later fully overwritten by main)
  off_conv_part<<<4 * BB * HH, 256, 0, stream>>>(x, b_off, ws_f, out);
  off_reduce<<<(65536 * 18 + 255) / 256, 256, 0, stream>>>(out, ws_f);
  akconv_main_mfma8<<<BB * HH * 2, 512, 0, stream>>>(ws_u, ws_f, out);
}

// Round 9
// 153.417 us; speedup vs baseline: 1.4645x; 1.4645x over previous
//
#include <hip/hip_runtime.h>
#include <math.h>

typedef __attribute__((ext_vector_type(8))) short short8;
typedef __attribute__((ext_vector_type(4))) float f32x4;

#define BB  4
#define C1  128
#define C2  256
#define HH  128
#define WW  128
#define NPT 9
#define HWN (HH*WW)

// ---- workspace byte offsets (all 256-aligned) ----
#define XT_OFF    0ull                        // bf16 xT[b][h][w][c]   : 16,777,216 B
#define WB3_OFF   16777216ull                 // bf16 wB3[n][ob][kc][lane][8] : 589,824 B
#define WOF32_OFF (WB3_OFF + 589824ull)       // f32  wof32[c][q][81]  :     82,944 B
#define BN_OFF    (WOF32_OFF + 82944ull)      // f32  bnA/bnB[256]     :      2,048 B
#define OFFP_OFF  (BN_OFF + 2048ull)          // f32  offp[pos][20]    :  5,242,880 B

__device__ __forceinline__ ushort f2bf(float f) {
  uint u = __builtin_bit_cast(uint, f);
  u += 0x7FFFu + ((u >> 16) & 1u);            // RNE
  return (ushort)(u >> 16);
}
__device__ __forceinline__ float bf2f(ushort u) {
  return __builtin_bit_cast(float, ((uint)u) << 16);
}

// ---------------- weight / BN prep ----------------
// wB3 element t: j=t&7, lane=(t>>3)&63, kc=(t>>9)&3, ob=(t>>11)&15, n=t>>15
//   -> o = ob*16 + (lane&15), c = kc*32 + (lane>>4)*8 + j
__global__ __launch_bounds__(256) void prep(
    const float* __restrict__ w_main, const float* __restrict__ w_off,
    const float* __restrict__ g, const float* __restrict__ be,
    const float* __restrict__ mu, const float* __restrict__ var,
    ushort* ws_u, float* ws_f) {
  int t = blockIdx.x * 256 + threadIdx.x;
  if (t < C1 * NPT * C2) {
    int j = t & 7, lane = (t >> 3) & 63, kc = (t >> 9) & 3;
    int ob = (t >> 11) & 15, n = t >> 15;
    int o = ob * 16 + (lane & 15);
    int c = kc * 32 + (lane >> 4) * 8 + j;
    ws_u[WB3_OFF / 2 + t] = f2bf(w_main[(o * C1 + c) * NPT + n]);
  } else if (t < C1 * NPT * C2 + 128 * 2 * 81) {  // wof32[(c*2+q)*81 + tap*9 + i]
    int e = t - C1 * NPT * C2;
    int c2 = e / 81, r81 = e - c2 * 81;
    int q = c2 & 1, c = c2 >> 1;
    int tap = r81 / 9, i = r81 - tap * 9;
    int oc = q * 9 + i;
    ws_f[WOF32_OFF / 4 + e] = w_off[(oc * C1 + c) * 9 + tap];
  } else if (t < C1 * NPT * C2 + 128 * 2 * 81 + C2) {
    int o = t - (C1 * NPT * C2 + 128 * 2 * 81);
    float inv = g[o] * rsqrtf(var[o] + 1e-5f);
    ws_f[BN_OFF / 4 + o] = inv;
    ws_f[BN_OFF / 4 + 256 + o] = be[o] - mu[o] * inv;
  }
}

// ---------------- x -> xT[b][h][w][c] bf16 (c-contiguous) ----------------
__global__ __launch_bounds__(256) void transpose_x(
    const float* __restrict__ x, ushort* ws_u) {
  __shared__ __align__(16) ushort tile[32][68];
  int bid = blockIdx.x;
  int wt = bid & 1, h = (bid >> 1) & 127, cb = (bid >> 8) & 3, b = bid >> 10;
  int c0 = cb * 32, w0 = wt * 64;
  int tid = threadIdx.x;
  int wl = tid & 63, rr = tid >> 6;
#pragma unroll
  for (int it = 0; it < 8; ++it) {
    int ci = it * 4 + rr;
    tile[ci][wl] = f2bf(x[(((size_t)b * C1 + c0 + ci) * HWN) + h * WW + w0 + wl]);
  }
  __syncthreads();
  int wl2 = tid >> 2, cg = tid & 3;
  short8 pk;
#pragma unroll
  for (int k = 0; k < 8; ++k) pk[k] = (short)tile[cg * 8 + k][wl2];
  *(short8*)(ws_u + XT_OFF / 2 +
             (((size_t)(b * HH + h) * WW + w0 + wl2) * C1 + c0 + cg * 8)) = pk;
}

// ---------------- fp32 offset conv, channel-split x4, no LDS, no barriers ----------------
__global__ __launch_bounds__(256) void off_conv_part(
    const float* __restrict__ x, const float* __restrict__ b_off,
    const float* __restrict__ ws_f, float* __restrict__ part) {
  int blk = blockIdx.x;
  int cg = blk & 3, bh = blk >> 2;
  int h = bh & 127, b = bh >> 7;
  int tid = threadIdx.x;
  int w = tid & 127, q = tid >> 7;
  int qu = __builtin_amdgcn_readfirstlane(q);
  const float* wq = ws_f + WOF32_OFF / 4 + qu * 81;
  const float* xb = x + ((size_t)b * C1 + cg * 32) * HWN;

  float acc[9];
#pragma unroll
  for (int i = 0; i < 9; ++i) acc[i] = (cg == 0) ? b_off[qu * 9 + i] : 0.f;

  int hc0 = (h >= 1) ? h - 1 : 0, hc2 = (h < 127) ? h + 1 : 127;
  int wc0 = (w >= 1) ? w - 1 : 0, wc2 = (w < 127) ? w + 1 : 127;
  bool vh0 = (h >= 1), vh2 = (h < 127);
  bool vw0 = (w >= 1), vw2 = (w < 127);
  int o[9];
  o[0] = hc0 * 128 + wc0; o[1] = hc0 * 128 + w; o[2] = hc0 * 128 + wc2;
  o[3] = h   * 128 + wc0; o[4] = h   * 128 + w; o[5] = h   * 128 + wc2;
  o[6] = hc2 * 128 + wc0; o[7] = hc2 * 128 + w; o[8] = hc2 * 128 + wc2;
  bool vm[9];
  vm[0] = vh0 && vw0; vm[1] = vh0; vm[2] = vh0 && vw2;
  vm[3] = vw0;        vm[4] = true; vm[5] = vw2;
  vm[6] = vh2 && vw0; vm[7] = vh2; vm[8] = vh2 && vw2;

  for (int ci = 0; ci < 32; ++ci) {
    const float* xc = xb + (size_t)ci * HWN;
    float xv[9];
#pragma unroll
    for (int k = 0; k < 9; ++k) {
      float r = xc[o[k]];
      xv[k] = vm[k] ? r : 0.f;
    }
    const float* wp = wq + (cg * 32 + ci) * 162;
#pragma unroll
    for (int tap = 0; tap < 9; ++tap)
#pragma unroll
      for (int i = 0; i < 9; ++i)
        acc[i] = fmaf(xv[tap], wp[tap * 9 + i], acc[i]);
  }
  int pos = (b * HH + h) * WW + w;
  float* pd = part + ((size_t)cg * 65536 + pos) * 20 + qu * 9;
#pragma unroll
  for (int i = 0; i < 9; ++i) pd[i] = acc[i];
}

// ---------------- reduce 4 partials -> offp ----------------
__global__ __launch_bounds__(256) void off_reduce(
    const float* __restrict__ part, float* __restrict__ ws_f) {
  int e = blockIdx.x * 256 + threadIdx.x;
  if (e >= 65536 * 18) return;
  int pos = e / 18, oc = e - pos * 18;
  size_t i0 = (size_t)pos * 20 + oc;
  float s = part[i0]
          + part[i0 + (size_t)65536 * 20]
          + part[i0 + (size_t)2 * 65536 * 20]
          + part[i0 + (size_t)3 * 65536 * 20];
  ws_f[OFFP_OFF / 4 + i0] = s;
}

// ---------------- fused gather + MFMA GEMM + BN + SiLU (8-wave) ----------------
#define ALDS_STRIDE 136   // ushorts per 64-pos row (128 + 8 pad)
__global__ __launch_bounds__(512) void akconv_main_mfma8(
    const ushort* ws_u, const float* ws_f, float* out) {
  __shared__ ushort sxy[576];                       // (x0<<8)|y0
  __shared__ __align__(16) f32x4 swgt[576];         // 4 bilinear weights, f32
  __shared__ __align__(16) ushort alds[2][64 * ALDS_STRIDE];

  int tid = threadIdx.x;
  int blk = blockIdx.x;
  // XCD-aware decode: each XCD (blk&7) owns one b-plane and one 64-row h-band
  int xcd = blk & 7, idx = blk >> 3;
  int b  = xcd >> 1;
  int h  = ((xcd & 1) << 6) + (idx >> 1);
  int wt = idx & 1;
  int w0 = wt * 64;
  const float* offp = ws_f + OFFP_OFF / 4;

  // phase A: bilinear sample (x0,y0) + 4 weights for 64 positions x 9 points
  for (int t = tid; t < 576; t += 512) {
    int n = t >> 6, wl = t & 63;
    int pos = (b * HH + h) * WW + w0 + wl;
    float ox = offp[pos * 20 + n];
    float oy = offp[pos * 20 + 9 + n];
    float px = ox + (float)(n / 3) + (float)h;
    float py = oy + (float)(n - (n / 3) * 3) + (float)(w0 + wl);
    px = fminf(fmaxf(px, 0.f), 127.f);
    py = fminf(fmaxf(py, 0.f), 127.f);
    float x0 = floorf(px), y0 = floorf(py);
    float x1 = fminf(x0 + 1.f, 127.f), y1 = fminf(y0 + 1.f, 127.f);
    f32x4 g;
    g[0] = (1.f + (x0 - px)) * (1.f + (y0 - py));
    g[1] = (1.f - (x1 - px)) * (1.f - (y1 - py));
    g[2] = (1.f + (x0 - px)) * (1.f - (y1 - py));
    g[3] = (1.f - (x1 - px)) * (1.f + (y0 - py));
    sxy[t] = (ushort)(((int)x0 << 8) | (int)y0);
    swgt[t] = g;
  }

  const char* xTb = (const char*)ws_u + (size_t)b * (HWN * 256);
  const ushort* wB3 = ws_u + WB3_OFF / 2;
  int lane = tid & 63, r = lane & 15, kg = lane >> 4;
  int obu = __builtin_amdgcn_readfirstlane(tid >> 6) * 2;  // wave's o-block (16-wide) base

  // per-thread build slots: two of (pos, 16B c-octet)
  int p0  = tid >> 4;                 // 0..31
  int p1  = p0 + 32;                  // 32..63
  int oct = tid & 15;
  int coff = oct * 16;                // byte offset within 256B c-row
  int wr0 = p0 * ALDS_STRIDE + oct * 8;
  int wr1 = p1 * ALDS_STRIDE + oct * 8;

  f32x4 acc[4][2];
#pragma unroll
  for (int mi = 0; mi < 4; ++mi)
#pragma unroll
    for (int oi = 0; oi < 2; ++oi) acc[mi][oi] = (f32x4)0.0f;

  __syncthreads();   // sxy/swgt visible

  short8 gv[2][4];
  f32x4 gw0, gw1;

#define GLOAD(nn)                                                       \
  {                                                                     \
    int e0 = sxy[(nn) * 64 + p0];                                       \
    int e1 = sxy[(nn) * 64 + p1];                                       \
    gw0 = swgt[(nn) * 64 + p0];                                         \
    gw1 = swgt[(nn) * 64 + p1];                                         \
    int ax0 = e0 >> 8, ay0 = e0 & 255;                                  \
    int ax1 = min(ax0 + 1, 127), ay1 = min(ay0 + 1, 127);               \
    int bx0 = e1 >> 8, by0 = e1 & 255;                                  \
    int bx1 = min(bx0 + 1, 127), by1 = min(by0 + 1, 127);               \
    gv[0][0] = *(const short8*)(xTb + (ax0 << 15) + (ay0 << 8) + coff); \
    gv[0][1] = *(const short8*)(xTb + (ax1 << 15) + (ay1 << 8) + coff); \
    gv[0][2] = *(const short8*)(xTb + (ax0 << 15) + (ay1 << 8) + coff); \
    gv[0][3] = *(const short8*)(xTb + (ax1 << 15) + (ay0 << 8) + coff); \
    gv[1][0] = *(const short8*)(xTb + (bx0 << 15) + (by0 << 8) + coff); \
    gv[1][1] = *(const short8*)(xTb + (bx1 << 15) + (by1 << 8) + coff); \
    gv[1][2] = *(const short8*)(xTb + (bx0 << 15) + (by1 << 8) + coff); \
    gv[1][3] = *(const short8*)(xTb + (bx1 << 15) + (by0 << 8) + coff); \
  }

#define GCOMBINE(bufb)                                                  \
  {                                                                     \
    short8 pk0, pk1;                                                    \
    _Pragma("unroll")                                                   \
    for (int j = 0; j < 8; ++j) {                                       \
      float f0 = gw0[0] * bf2f((ushort)gv[0][0][j])                     \
               + gw0[1] * bf2f((ushort)gv[0][1][j])                     \
               + gw0[2] * bf2f((ushort)gv[0][2][j])                     \
               + gw0[3] * bf2f((ushort)gv[0][3][j]);                    \
      float f1 = gw1[0] * bf2f((ushort)gv[1][0][j])                     \
               + gw1[1] * bf2f((ushort)gv[1][1][j])                     \
               + gw1[2] * bf2f((ushort)gv[1][2][j])                     \
               + gw1[3] * bf2f((ushort)gv[1][3][j]);                    \
      pk0[j] = (short)f2bf(f0);                                         \
      pk1[j] = (short)f2bf(f1);                                         \
    }                                                                   \
    *(short8*)(&alds[bufb][wr0]) = pk0;                                 \
    *(short8*)(&alds[bufb][wr1]) = pk1;                                 \
  }

  // prologue: build n=0 into buf 0
  GLOAD(0);
  GCOMBINE(0);
  __syncthreads();

  for (int n = 0; n < 9; ++n) {
    int buf = n & 1;
    // 1) issue next-n gathers (latency hides under MFMA phase)
    if (n < 8) GLOAD(n + 1);
    // 2) MFMA over the current 128-channel slab; B-loads contiguous 1KB/wave
#pragma unroll
    for (int kc = 0; kc < 4; ++kc) {
      short8 b0 = *(const short8*)(wB3 + ((((size_t)(n * 16 + obu) * 4 + kc) * 64 + lane) * 8));
      short8 b1 = *(const short8*)(wB3 + ((((size_t)(n * 16 + obu + 1) * 4 + kc) * 64 + lane) * 8));
#pragma unroll
      for (int mi = 0; mi < 4; ++mi) {
        short8 a = *(const short8*)(&alds[buf][(mi * 16 + r) * ALDS_STRIDE + (kc * 4 + kg) * 8]);
        acc[mi][0] = __builtin_amdgcn_mfma_f32_16x16x32_bf16(b0, a, acc[mi][0], 0, 0, 0);
        acc[mi][1] = __builtin_amdgcn_mfma_f32_16x16x32_bf16(b1, a, acc[mi][1], 0, 0, 0);
      }
    }
    // 3) combine + write next slab
    if (n < 8) GCOMBINE(buf ^ 1);
    __syncthreads();
  }
#undef GLOAD
#undef GCOMBINE

  // epilogue: BN + SiLU, coalesced along w (col = position)
  const float* bnA = ws_f + BN_OFF / 4;
  const float* bnB = bnA + 256;
  int owu = obu * 16;
#pragma unroll
  for (int oi = 0; oi < 2; ++oi) {
#pragma unroll
    for (int mi = 0; mi < 4; ++mi) {
#pragma unroll
      for (int j = 0; j < 4; ++j) {
        int o = owu + oi * 16 + kg * 4 + j;
        float sA = bnA[o], sB = bnB[o];
        float v = acc[mi][oi][j] * sA + sB;
        float sv = v / (1.f + __expf(-v));
        out[(((size_t)b * C2 + o) * HWN) + h * WW + w0 + mi * 16 + r] = sv;
      }
    }
  }
}

extern "C" void kernel_launch(void* const* d_in, const int* in_sizes, int n_in,
                              void* d_out, int out_size, void* d_ws, size_t ws_size,
                              hipStream_t stream) {
  const float* x        = (const float*)d_in[0];
  const float* w_off    = (const float*)d_in[1];
  const float* b_off    = (const float*)d_in[2];
  const float* w_main   = (const float*)d_in[3];
  const float* bn_gamma = (const float*)d_in[4];
  const float* bn_beta  = (const float*)d_in[5];
  const float* bn_mean  = (const float*)d_in[6];
  const float* bn_var   = (const float*)d_in[7];
  ushort* ws_u = (ushort*)d_ws;
  float*  ws_f = (float*)d_ws;
  float*  out  = (float*)d_out;

  int prep_tasks = C1 * NPT * C2 + 128 * 2 * 81 + C2;   // 315904
  prep<<<(prep_tasks + 255) / 256, 256, 0, stream>>>(
      w_main, w_off, bn_gamma, bn_beta, bn_mean, bn_var, ws_u, ws_f);
  transpose_x<<<BB * 4 * HH * 2, 256, 0, stream>>>(x, ws_u);
  // offset conv: partials into d_out scratch (later fully overwritten by main)
  off_conv_part<<<4 * BB * HH, 256, 0, stream>>>(x, b_off, ws_f, out);
  off_reduce<<<(65536 * 18 + 255) / 256, 256, 0, stream>>>(out, ws_f);
  akconv_main_mfma8<<<BB * HH * 2, 512, 0, stream>>>(ws_u, ws_f, out);
}